// Round 7
// baseline (113.301 us; speedup 1.0000x reference)
//
#include <hip/hip_runtime.h>
#include <hip/hip_bf16.h>

// B=16, C=64, CQ=8, H=W=128
typedef unsigned short u16;
typedef __attribute__((ext_vector_type(8))) short    bf16x8;
typedef __attribute__((ext_vector_type(8))) unsigned short us8;
typedef __attribute__((ext_vector_type(4))) unsigned short us4;
typedef __attribute__((ext_vector_type(4))) float    f32x4;
typedef __attribute__((ext_vector_type(2))) unsigned int u32x2;

__device__ __forceinline__ u16 f2bf(float f) {
    unsigned u = __float_as_uint(f);
    return (u16)((u + 0x7FFFu + ((u >> 16) & 1u)) >> 16);
}
__device__ __forceinline__ float bf2f(u16 v) {
    return __uint_as_float((unsigned)v << 16);
}

// ---------------------------------------------------------------------------
// Kernel 0: W prep. Packs Wv/Wq/Wk into bf16 B-frag slots
// Wpk[nt(5)][kt(2)][lane(64)][8]; biasf[80] = {bv, bq, bk}.
// ---------------------------------------------------------------------------
__global__ __launch_bounds__(256) void wprep_kernel(
    const float* __restrict__ Wq, const float* __restrict__ bq,
    const float* __restrict__ Wk, const float* __restrict__ bk,
    const float* __restrict__ Wv, const float* __restrict__ bv,
    u16* __restrict__ Wpk, float* __restrict__ biasf)
{
    int t = threadIdx.x;
    for (int s = t; s < 640; s += 256) {
        int nt = s >> 7;
        int kt = (s >> 6) & 1;
        int l  = s & 63;
        int n  = (nt << 4) | (l & 15);
        int k0 = kt * 32 + ((l >> 4) << 3);
        const float* row;
        if (n < 64) row = Wv + n * 64;
        else if (n < 72) row = Wq + (n - 64) * 64;
        else row = Wk + (n - 72) * 64;
        us8 o;
#pragma unroll
        for (int j = 0; j < 8; j++) o[j] = f2bf(row[k0 + j]);
        *(us8*)&Wpk[s * 8] = o;
    }
    if (t < 80) {
        float bb;
        if (t < 64) bb = bv[t];
        else if (t < 72) bb = bq[t - 64];
        else bb = bk[t - 72];
        biasf[t] = bb;
    }
}

// ---------------------------------------------------------------------------
// Kernel 1: projections via MFMA. Block = 256 pixels, 512 thr = 8 waves.
// ---------------------------------------------------------------------------
#define PH 258   // LDS x-tile row stride (u16); ==2 mod 4 -> conflict-free frags
__global__ __launch_bounds__(512) void proj_kernel(
    const float* __restrict__ x, const u16* __restrict__ Wpk,
    const float* __restrict__ biasf,
    u16* __restrict__ vb16, u16* __restrict__ qkTr)
{
    __shared__ u16 Xh[64 * PH];   // 33 KB

    int t = threadIdx.x;
    int bid = blockIdx.x;
    int wg = ((bid & 7) << 7) | (bid >> 3);   // b-matched XCD swizzle
    int b = wg >> 6;
    int hw0 = (wg & 63) << 8;
    const float* xb = x + ((long)b << 20) + hw0;

#pragma unroll
    for (int it = 0; it < 8; it++) {
        int c = it * 8 + (t >> 6);
        int pix = (t & 63) << 2;
        float4 xv = *(const float4*)&xb[(c << 14) + pix];
        unsigned lo = ((unsigned)f2bf(xv.y) << 16) | f2bf(xv.x);
        unsigned hi = ((unsigned)f2bf(xv.w) << 16) | f2bf(xv.z);
        unsigned* dst = (unsigned*)&Xh[c * PH + pix];
        dst[0] = lo; dst[1] = hi;
    }
    __syncthreads();

    int wv = t >> 6, l = t & 63;
    int m16 = l & 15, kg = l >> 4;
    int pixb = wv << 5;

    bf16x8 af[2][2];
#pragma unroll
    for (int mt = 0; mt < 2; mt++) {
        int pix = pixb + (mt << 4) + m16;
#pragma unroll
        for (int kt = 0; kt < 2; kt++) {
            us8 a;
#pragma unroll
            for (int j = 0; j < 8; j++)
                a[j] = Xh[(kt * 32 + (kg << 3) + j) * PH + pix];
            af[mt][kt] = (bf16x8)a;
        }
    }

    f32x4 acc[2][5];
#pragma unroll
    for (int nt = 0; nt < 5; nt++) {
        float bb = biasf[(nt << 4) + m16];
        f32x4 binit = {bb, bb, bb, bb};
        bf16x8 b0 = *(const bf16x8*)&Wpk[(((nt << 1) + 0) << 9) + (l << 3)];
        bf16x8 b1 = *(const bf16x8*)&Wpk[(((nt << 1) + 1) << 9) + (l << 3)];
#pragma unroll
        for (int mt = 0; mt < 2; mt++) {
            f32x4 a_ = binit;
            a_ = __builtin_amdgcn_mfma_f32_16x16x32_bf16(af[mt][0], b0, a_, 0, 0, 0);
            a_ = __builtin_amdgcn_mfma_f32_16x16x32_bf16(af[mt][1], b1, a_, 0, 0, 0);
            acc[mt][nt] = a_;
        }
    }

    long vbase = ((long)b << 20) + hw0;
#pragma unroll
    for (int mt = 0; mt < 2; mt++) {
        int pix0 = pixb + (mt << 4) + (kg << 2);
#pragma unroll
        for (int nt = 0; nt < 4; nt++) {
            int c = (nt << 4) + m16;
            us4 pkd = { f2bf(acc[mt][nt][0]), f2bf(acc[mt][nt][1]),
                        f2bf(acc[mt][nt][2]), f2bf(acc[mt][nt][3]) };
            *(us4*)&vb16[vbase + (c << 14) + pix0] = pkd;
        }
#pragma unroll
        for (int r = 0; r < 4; r++)
            qkTr[((((long)(b << 14)) + hw0 + pix0 + r) << 4) + m16] = f2bf(acc[mt][4][r]);
    }
}

// ---------------------------------------------------------------------------
// Kernel 2: v transpose: vb16[b][c][g][w] -> vTc[b][w][c][g] (bf16).
// ---------------------------------------------------------------------------
__global__ __launch_bounds__(256) void vtrans_kernel(
    const u16* __restrict__ vb16, u16* __restrict__ vTc)
{
    __shared__ u16 tile[32][33];
    int t = threadIdx.x;
    int bid = blockIdx.x;
    int vwg = ((bid & 7) << 11) | (bid >> 3);  // b-matched XCD swizzle
    int b = vwg >> 10;
    int c = (vwg >> 4) & 63;
    int g0 = ((vwg >> 2) & 3) * 32, w0 = (vwg & 3) * 32;
    const u16* src = vb16 + ((b * 64 + c) << 14);
#pragma unroll
    for (int it = 0; it < 4; it++) {
        int i = it * 8 + (t >> 5), j = t & 31;
        tile[i][j] = src[(g0 + i) * 128 + w0 + j];
    }
    __syncthreads();
    int j = t >> 3, i4 = (t & 7) * 4;
    us4 o = { tile[i4][j], tile[i4 + 1][j], tile[i4 + 2][j], tile[i4 + 3][j] };
    *(us4*)&vTc[((b * 128 + w0 + j) * 64 + c) * 128 + g0 + i4] = o;
}

// ---------------------------------------------------------------------------
// Kernel 3: column attention. Block (b,w), 512 thr = 8 waves.
// QK^T -> exp (diag masked) -> Epk; PV = V^T(A) x E(B): D[c][h].
// Writes accHt[b][w][h][c] bf16 + sH[b][w][h].
// ---------------------------------------------------------------------------
__global__ __launch_bounds__(512) void colH_kernel(
    const u16* __restrict__ qkTr, const u16* __restrict__ vTc,
    u16* __restrict__ accHt, float* __restrict__ sH)
{
    __shared__ u16 Qpk[129 * 8];
    __shared__ u16 Kpk[129 * 8];
    __shared__ u16 Epk[2048 * 8];
    __shared__ u16 Vs[1024 * 8];

    int t = threadIdx.x;
    int bid = blockIdx.x;
    int wg = ((bid & 7) << 8) | (bid >> 3);
    int b = wg >> 7, w = wg & 127;

    if (t < 128) {
        const u16* p = qkTr + (((long)((b << 14) + t * 128 + w)) << 4);
        *(us8*)&Qpk[t * 8] = *(const us8*)p;
        *(us8*)&Kpk[t * 8] = *(const us8*)(p + 8);
    } else if (t == 128) {
        us8 z = {0,0,0,0,0,0,0,0};
        *(us8*)&Qpk[128 * 8] = z;
        *(us8*)&Kpk[128 * 8] = z;
    }

    const u16* vB = vTc + ((long)(b * 128 + w) << 13);
#pragma unroll
    for (int m = t; m < 1024; m += 512) {
        int c = m >> 4, s = m & 15;
        int src = (c << 4) | (s & 8) | ((s ^ c) & 7);
        *(us8*)&Vs[m << 3] = *(const us8*)&vB[src << 3];
    }
    __syncthreads();

    int wv = t >> 6, l = t & 63;
    int m16 = l & 15, kg = l >> 4;
    f32x4 zero4 = {0.f, 0.f, 0.f, 0.f};

    int gt = wv;
    bf16x8 afr;
    { int sl = (kg == 0) ? (gt * 16 + m16) : 128;
      afr = *(const bf16x8*)&Kpk[sl * 8]; }
    int kgr = ((gt & 1) << 1) | (kg >> 1);
    int jb  = (kg & 1) << 2;
    int gbase = gt * 16 + kg * 4;
#pragma unroll
    for (int ht = 0; ht < 8; ht++) {
        int slB = (kg == 0) ? (ht * 16 + m16) : 128;
        bf16x8 bfr = *(const bf16x8*)&Qpk[slB * 8];
        f32x4 e = __builtin_amdgcn_mfma_f32_16x16x32_bf16(afr, bfr, zero4, 0, 0, 0);
        u16 u0[4];
#pragma unroll
        for (int r = 0; r < 4; r++) {
            int g = gbase + r, h = ht * 16 + m16;
            float val = (g == h) ? 0.f : __expf(e[r]);
            u0[r] = f2bf(val);
        }
        int eidx = ((((ht << 2) | (gt >> 1)) * 64 + kgr * 16 + m16) << 3) + jb;
        u32x2 pk2;
        pk2.x = (unsigned)u0[0] | ((unsigned)u0[1] << 16);
        pk2.y = (unsigned)u0[2] | ((unsigned)u0[3] << 16);
        *(u32x2*)&Epk[eidx] = pk2;
    }
    __syncthreads();

    int mt = wv;
    bf16x8 bE[4];
#pragma unroll
    for (int kt = 0; kt < 4; kt++)
        bE[kt] = *(const bf16x8*)&Epk[(((mt << 2) + kt) * 64 + l) << 3];

    bf16x8 ones;
    short ov = (m16 == 0) ? (short)0x3F80 : (short)0;
#pragma unroll
    for (int j = 0; j < 8; j++) ones[j] = ov;

    f32x4 acc[5];
#pragma unroll
    for (int i = 0; i < 5; i++) acc[i] = zero4;

#pragma unroll
    for (int ct = 0; ct < 4; ct++) {
#pragma unroll
        for (int kt = 0; kt < 4; kt++) {
            int slot = ((ct * 16 + m16) << 4) | ((((kt << 2) | kg)) ^ (m16 & 7));
            bf16x8 aV = *(const bf16x8*)&Vs[slot << 3];
            acc[ct] = __builtin_amdgcn_mfma_f32_16x16x32_bf16(aV, bE[kt], acc[ct], 0, 0, 0);
        }
    }
#pragma unroll
    for (int kt = 0; kt < 4; kt++)
        acc[4] = __builtin_amdgcn_mfma_f32_16x16x32_bf16(ones, bE[kt], acc[4], 0, 0, 0);

    long obase = (((long)(b * 128 + w)) * 128 + mt * 16 + m16) * 64;
#pragma unroll
    for (int ct = 0; ct < 4; ct++) {
        us4 pkd = { f2bf(acc[ct][0]), f2bf(acc[ct][1]), f2bf(acc[ct][2]), f2bf(acc[ct][3]) };
        *(us4*)&accHt[obase + ct * 16 + kg * 4] = pkd;
    }
    if (kg == 0)
        sH[(b * 128 + w) * 128 + mt * 16 + m16] = acc[4][0];
}

// ---------------------------------------------------------------------------
// Kernel 4: row attention + fused finalize. Block (b,h), 512 thr = 8 waves.
// Finalize inputs (sH, accHt, x) hoisted to kernel start; sW broadcast
// in-wave via shfl; gr and accH folded into the single outS staging pass.
// ---------------------------------------------------------------------------
__global__ __launch_bounds__(512) void rowW_fin_kernel(
    const u16* __restrict__ qkTr, const u16* __restrict__ vb16,
    const u16* __restrict__ accHt, const float* __restrict__ sH,
    const float* __restrict__ x, const float* __restrict__ gamma,
    float* __restrict__ out)
{
    __shared__ u16 Qpk[129 * 8];
    __shared__ u16 Kpk[129 * 8];
    __shared__ union FU {
        struct { u16 Epk[2048 * 8]; u16 Vs[1024 * 8]; } s;   // 48 KB
        struct { float outS[64 * 132]; } f;                   // 33 KB
    } uu;

    int t = threadIdx.x;
    int bid = blockIdx.x;
    int wg = ((bid & 7) << 8) | (bid >> 3);
    int b = wg >> 7, h = wg & 127;
    float gm = gamma[0];

    int wv = t >> 6, l = t & 63;
    int m16 = l & 15, kg = l >> 4;
    int wcol = wv * 16 + m16;

    // ---- hoisted finalize loads (independent of all in-kernel compute) ----
    float sHreg = sH[(b * 128 + wcol) * 128 + h];
    us4 hA[4];
    long hbase = (((long)(b * 128 + wcol)) * 128 + h) * 64 + (kg << 2);
#pragma unroll
    for (int ct = 0; ct < 4; ct++)
        hA[ct] = *(const us4*)&accHt[hbase + ct * 16];
    long obase = ((long)b << 20) + (h << 7);
    float4 xv[4];
#pragma unroll
    for (int p = 0; p < 4; p++) {
        int q = t + 512 * p;
        int c = q >> 5, w4 = (q & 31) << 2;
        xv[p] = *(const float4*)&x[obase + ((long)c << 14) + w4];
    }

    // ---- staging ----
    if (t < 128) {
        const u16* p = qkTr + (((long)((b << 14) + h * 128 + t)) << 4);
        *(us8*)&Qpk[t * 8] = *(const us8*)p;
        *(us8*)&Kpk[t * 8] = *(const us8*)(p + 8);
    } else if (t == 128) {
        us8 z = {0,0,0,0,0,0,0,0};
        *(us8*)&Qpk[128 * 8] = z;
        *(us8*)&Kpk[128 * 8] = z;
    }

    const u16* vB = vb16 + ((long)b << 20) + (h << 7);
#pragma unroll
    for (int m = t; m < 1024; m += 512) {
        int c = m >> 4, s = m & 15;
        int src = (s & 8) | ((s ^ c) & 7);
        *(us8*)&uu.s.Vs[m << 3] = *(const us8*)&vB[((long)c << 14) + (src << 3)];
    }
    __syncthreads();

    f32x4 zero4 = {0.f, 0.f, 0.f, 0.f};

    // ---- QK^T: E[v][w], no diagonal mask ----
    int gt = wv;
    bf16x8 afr;
    { int sl = (kg == 0) ? (gt * 16 + m16) : 128;
      afr = *(const bf16x8*)&Kpk[sl * 8]; }
    int kgr = ((gt & 1) << 1) | (kg >> 1);
    int jb  = (kg & 1) << 2;
#pragma unroll
    for (int ht = 0; ht < 8; ht++) {
        int slB = (kg == 0) ? (ht * 16 + m16) : 128;
        bf16x8 bfr = *(const bf16x8*)&Qpk[slB * 8];
        f32x4 e = __builtin_amdgcn_mfma_f32_16x16x32_bf16(afr, bfr, zero4, 0, 0, 0);
        u16 u0[4];
#pragma unroll
        for (int r = 0; r < 4; r++) u0[r] = f2bf(__expf(e[r]));
        int eidx = ((((ht << 2) | (gt >> 1)) * 64 + kgr * 16 + m16) << 3) + jb;
        u32x2 pk2;
        pk2.x = (unsigned)u0[0] | ((unsigned)u0[1] << 16);
        pk2.y = (unsigned)u0[2] | ((unsigned)u0[3] << 16);
        *(u32x2*)&uu.s.Epk[eidx] = pk2;
    }
    __syncthreads();

    // ---- PV: D[c][w] ----
    int mt = wv;
    bf16x8 bE[4];
#pragma unroll
    for (int kt = 0; kt < 4; kt++)
        bE[kt] = *(const bf16x8*)&uu.s.Epk[(((mt << 2) + kt) * 64 + l) << 3];

    bf16x8 ones;
    short ov = (m16 == 0) ? (short)0x3F80 : (short)0;
#pragma unroll
    for (int j = 0; j < 8; j++) ones[j] = ov;

    f32x4 acc[5];
#pragma unroll
    for (int i = 0; i < 5; i++) acc[i] = zero4;

#pragma unroll
    for (int ct = 0; ct < 4; ct++) {
#pragma unroll
        for (int kt = 0; kt < 4; kt++) {
            int slot = ((ct * 16 + m16) << 4) | ((((kt << 2) | kg)) ^ (m16 & 7));
            bf16x8 aV = *(const bf16x8*)&uu.s.Vs[slot << 3];
            acc[ct] = __builtin_amdgcn_mfma_f32_16x16x32_bf16(aV, bE[kt], acc[ct], 0, 0, 0);
        }
    }
#pragma unroll
    for (int kt = 0; kt < 4; kt++)
        acc[4] = __builtin_amdgcn_mfma_f32_16x16x32_bf16(ones, bE[kt], acc[4], 0, 0, 0);

    // ---- sW broadcast (lane m16 holds the ones-row value for column wcol) ----
    float sWv_ = __shfl(acc[4][0], m16, 64);
    float grv = gm / (sHreg + sWv_);

    __syncthreads();   // all Epk/Vs reads done; union flips to outS

    // ---- F0: single fused staging pass: outS = gr*(accW + accH) ----
#pragma unroll
    for (int ct = 0; ct < 4; ct++) {
#pragma unroll
        for (int r = 0; r < 4; r++)
            uu.f.outS[(ct * 16 + (kg << 2) + r) * 132 + wcol] =
                grv * (acc[ct][r] + bf2f(hA[ct][r]));
    }
    __syncthreads();

    // ---- F3: coalesced out = outS + x ----
#pragma unroll
    for (int p = 0; p < 4; p++) {
        int q = t + 512 * p;
        int c = q >> 5, w4 = (q & 31) << 2;
        float4 tv = *(float4*)&uu.f.outS[c * 132 + w4];
        float4 r;
        r.x = tv.x + xv[p].x;
        r.y = tv.y + xv[p].y;
        r.z = tv.z + xv[p].z;
        r.w = tv.w + xv[p].w;
        *(float4*)&out[obase + ((long)c << 14) + w4] = r;
    }
}

extern "C" void kernel_launch(void* const* d_in, const int* in_sizes, int n_in,
                              void* d_out, int out_size, void* d_ws, size_t ws_size,
                              hipStream_t stream) {
    const float* x     = (const float*)d_in[0];
    const float* Wq    = (const float*)d_in[1];
    const float* bq    = (const float*)d_in[2];
    const float* Wk    = (const float*)d_in[3];
    const float* bk    = (const float*)d_in[4];
    const float* Wv    = (const float*)d_in[5];
    const float* bv    = (const float*)d_in[6];
    const float* gamma = (const float*)d_in[7];
    float* out = (float*)d_out;

    u16* vb16  = (u16*)d_ws;                 // 16,777,216 u16 (32MB)
    u16* vTc   = vb16 + 16777216;            // 16,777,216 u16 (32MB)
    u16* qkTr  = vTc + 16777216;             // 4,194,304 u16 (8MB)
    u16* accHt = qkTr + 4194304;             // 16,777,216 u16 (32MB)
    float* sH  = (float*)(accHt + 16777216); // 262,144 f32 (1MB)
    u16* Wpk   = (u16*)(sH + 262144);        // 5,120 u16
    float* biasf = (float*)(Wpk + 5120);     // 80 f32

    wprep_kernel<<<1, 256, 0, stream>>>(Wq, bq, Wk, bk, Wv, bv, Wpk, biasf);
    proj_kernel<<<1024, 512, 0, stream>>>(x, Wpk, biasf, vb16, qkTr);
    vtrans_kernel<<<16384, 256, 0, stream>>>(vb16, vTc);
    colH_kernel<<<2048, 512, 0, stream>>>(qkTr, vTc, accHt, sH);
    rowW_fin_kernel<<<2048, 512, 0, stream>>>(qkTr, vb16, accHt, sH, x, gamma, out);
}